// Round 3
// baseline (1213.790 us; speedup 1.0000x reference)
//
#include <hip/hip_runtime.h>
#include <math.h>

#define N_NODES 100000
#define N_FEAT  512
#define HIDDEN  128
#define N_CLASS 16
#define N_EDGES 3200000
#define ALPHA   0.25f

#define NB   782          // ceil(100000/128) buckets of 128 nodes
#define CAP  4608         // bucket capacity: mean 4096, std 64 -> +8 sigma
#define OCAP 65536        // overflow list capacity (pairs)

typedef __attribute__((ext_vector_type(8))) short short8;
typedef __attribute__((ext_vector_type(4))) float float4v;

__device__ inline short f2b(float f) {
    union { float f; unsigned u; } c; c.f = f;
    unsigned r = c.u + 0x7FFF + ((c.u >> 16) & 1);   // round-to-nearest-even
    return (short)(r >> 16);
}

// ---------------------------------------------------------------------------
// prep: W1t_bf[n=128][k=512] = bf16(W1[k][n]);  W2t_bf[n=16][k=128] = bf16(W2[k][n])
// ---------------------------------------------------------------------------
__global__ void prep_kernel(const float* __restrict__ W1, const float* __restrict__ W2,
                            short* __restrict__ W1t, short* __restrict__ W2t) {
    int t = blockIdx.x * 256 + threadIdx.x;
    if (t < N_FEAT * HIDDEN) {                 // t = n*512 + k
        int k = t & 511, n = t >> 9;
        W1t[t] = f2b(W1[(size_t)k * HIDDEN + n]);
    }
    int t2 = t - N_FEAT * HIDDEN;
    if (t2 >= 0 && t2 < HIDDEN * N_CLASS) {    // t2 = n*128 + k
        int k = t2 & 127, n = t2 >> 7;
        W2t[t2] = f2b(W2[(size_t)k * N_CLASS + n]);
    }
}

// ---------------------------------------------------------------------------
// Fused MLP via MFMA: local = relu(x@W1)@W2, bf16 inputs / fp32 accum
// ---------------------------------------------------------------------------
__global__ __launch_bounds__(256) void mlp_mfma(const float* __restrict__ x,
                                                const short* __restrict__ W1t,
                                                const short* __restrict__ W2t,
                                                float* __restrict__ local_out) {
    __shared__ __align__(16) short As[128 * 32];
    __shared__ __align__(16) short Bts[128 * 32];
    __shared__ __align__(16) short Hs[128 * 136];
    __shared__ __align__(16) short W2ts[16 * 136];

    const int tid  = threadIdx.x;
    const int wave = tid >> 6;
    const int wl   = tid & 63;
    const int lane15 = wl & 15;
    const int quad   = wl >> 4;
    const long block_row = (long)blockIdx.x * 128;

    {
        int n = tid >> 4, koff = (tid & 15) * 8;
        *(short8*)&W2ts[n * 136 + koff] = *(const short8*)&W2t[n * 128 + koff];
    }

    float4v acc[4][4];
#pragma unroll
    for (int i = 0; i < 4; ++i)
#pragma unroll
        for (int j = 0; j < 4; ++j) acc[i][j] = (float4v){0.f, 0.f, 0.f, 0.f};

    const int wr0 = (wave >> 1) * 64;
    const int wc0 = (wave & 1) * 64;

    for (int k0 = 0; k0 < N_FEAT; k0 += 32) {
#pragma unroll
        for (int l = 0; l < 2; ++l) {
            int c = tid + l * 256;
            int row = c >> 2, off = (c & 3) * 8;
            long grow = block_row + row;
            float4 v0 = make_float4(0.f, 0.f, 0.f, 0.f), v1 = v0;
            if (grow < N_NODES) {
                const float* p = x + grow * N_FEAT + k0 + off;
                v0 = *(const float4*)p;
                v1 = *(const float4*)(p + 4);
            }
            short8 h;
            h[0] = f2b(v0.x); h[1] = f2b(v0.y); h[2] = f2b(v0.z); h[3] = f2b(v0.w);
            h[4] = f2b(v1.x); h[5] = f2b(v1.y); h[6] = f2b(v1.z); h[7] = f2b(v1.w);
            *(short8*)&As[row * 32 + off] = h;
        }
#pragma unroll
        for (int l = 0; l < 2; ++l) {
            int c = tid + l * 256;
            int n = c >> 2, koff = (c & 3) * 8;
            *(short8*)&Bts[n * 32 + koff] = *(const short8*)&W1t[n * 512 + k0 + koff];
        }
        __syncthreads();

        short8 af[4], bfr[4];
#pragma unroll
        for (int i = 0; i < 4; ++i)
            af[i] = *(short8*)&As[(wr0 + i * 16 + lane15) * 32 + quad * 8];
#pragma unroll
        for (int j = 0; j < 4; ++j)
            bfr[j] = *(short8*)&Bts[(wc0 + j * 16 + lane15) * 32 + quad * 8];
#pragma unroll
        for (int i = 0; i < 4; ++i)
#pragma unroll
            for (int j = 0; j < 4; ++j)
                acc[i][j] = __builtin_amdgcn_mfma_f32_16x16x32_bf16(af[i], bfr[j], acc[i][j], 0, 0, 0);
        __syncthreads();
    }

#pragma unroll
    for (int i = 0; i < 4; ++i)
#pragma unroll
        for (int j = 0; j < 4; ++j)
#pragma unroll
            for (int r = 0; r < 4; ++r) {
                int row = wr0 + i * 16 + quad * 4 + r;
                int colh = wc0 + j * 16 + lane15;
                Hs[row * 136 + colh] = f2b(fmaxf(acc[i][j][r], 0.f));
            }
    __syncthreads();

    float4v acc2[2];
    acc2[0] = (float4v){0.f, 0.f, 0.f, 0.f};
    acc2[1] = acc2[0];
#pragma unroll
    for (int ks = 0; ks < 4; ++ks) {
        short8 a0 = *(short8*)&Hs[(wave * 32 + lane15) * 136 + ks * 32 + quad * 8];
        short8 a1 = *(short8*)&Hs[(wave * 32 + 16 + lane15) * 136 + ks * 32 + quad * 8];
        short8 b  = *(short8*)&W2ts[lane15 * 136 + ks * 32 + quad * 8];
        acc2[0] = __builtin_amdgcn_mfma_f32_16x16x32_bf16(a0, b, acc2[0], 0, 0, 0);
        acc2[1] = __builtin_amdgcn_mfma_f32_16x16x32_bf16(a1, b, acc2[1], 0, 0, 0);
    }
#pragma unroll
    for (int i2 = 0; i2 < 2; ++i2)
#pragma unroll
        for (int r = 0; r < 4; ++r) {
            long grow = block_row + wave * 32 + i2 * 16 + quad * 4 + r;
            if (grow < N_NODES)
                local_out[grow * N_CLASS + lane15] = acc2[i2][r];
        }
}

// ---------------------------------------------------------------------------
// passA: bin edges into NB buckets of 128 src-nodes. Packed (src&127)<<17 | dst.
// ---------------------------------------------------------------------------
__global__ void bucket_scatter(const int* __restrict__ src, const int* __restrict__ dst,
                               int* __restrict__ bcount, unsigned* __restrict__ bbuf,
                               int* __restrict__ odeg, int* __restrict__ ocount,
                               int* __restrict__ obuf) {
    int e = blockIdx.x * 256 + threadIdx.x;
    if (e >= N_EDGES) return;
    int s = src[e], d = dst[e];
    int b = s >> 7;
    int pos = atomicAdd(&bcount[b], 1);
    if (pos < CAP) {
        bbuf[(size_t)b * CAP + pos] = ((unsigned)(s & 127) << 17) | (unsigned)d;
    } else {
        atomicAdd(&odeg[s], 1);
        int op = atomicAdd(ocount, 1);
        if (op < OCAP) { obuf[2 * op] = s; obuf[2 * op + 1] = d; }
    }
}

// ---------------------------------------------------------------------------
// bscan: exclusive scan of NB bucket totals -> bbase. One value per thread.
// ---------------------------------------------------------------------------
__global__ __launch_bounds__(1024) void bscan_kernel(const int* __restrict__ bcount,
                                                     int* __restrict__ bbase,
                                                     int* __restrict__ row_ptr) {
    __shared__ int s[1024];
    int tid = threadIdx.x;
    int v = (tid < NB) ? bcount[tid] : 0;
    s[tid] = v;
    __syncthreads();
    for (int off = 1; off < 1024; off <<= 1) {
        int t = (tid >= off) ? s[tid - off] : 0;
        __syncthreads();
        s[tid] += t;
        __syncthreads();
    }
    if (tid < NB) bbase[tid] = s[tid] - v;
    if (tid == 0) row_ptr[N_NODES] = N_EDGES;
}

// ---------------------------------------------------------------------------
// passB: per-bucket degree count (LDS, no global atomics), local scan,
// row_ptr/scale/cursor write, then LDS-cursor placement into contiguous col
// window. Replaces hist + scatter.
// ---------------------------------------------------------------------------
__global__ __launch_bounds__(256) void bucket_build(const unsigned* __restrict__ bbuf,
                                                    const int* __restrict__ bcount,
                                                    const int* __restrict__ bbase,
                                                    const int* __restrict__ odeg,
                                                    int* __restrict__ row_ptr,
                                                    float* __restrict__ scale,
                                                    int* __restrict__ cursor,
                                                    int* __restrict__ col) {
    __shared__ int lcnt[128];
    __shared__ int ssc[128];
    __shared__ int lcur[128];

    int b = blockIdx.x;
    int tid = threadIdx.x;
    int node0 = b << 7;
    int nn = N_NODES - node0; if (nn > 128) nn = 128;

    if (tid < 128) lcnt[tid] = 0;
    __syncthreads();

    int n = bcount[b]; if (n > CAP) n = CAP;
    const unsigned* bb = bbuf + (size_t)b * CAP;
    for (int i = tid; i < n; i += 256)
        atomicAdd(&lcnt[bb[i] >> 17], 1);
    __syncthreads();

    // block scan of per-node totals (in-bucket + overflow)
    int val = 0, od = 0;
    if (tid < nn) { od = odeg[node0 + tid]; val = lcnt[tid] + od; }
    if (tid < 128) ssc[tid] = val;
    __syncthreads();
    for (int off = 1; off < 128; off <<= 1) {
        int t = (tid >= off && tid < 128) ? ssc[tid - off] : 0;
        __syncthreads();
        if (tid < 128) ssc[tid] += t;
        __syncthreads();
    }

    if (tid < nn) {
        int start = bbase[b] + ssc[tid] - val;
        int node = node0 + tid;
        row_ptr[node] = start;
        scale[node] = (1.0f - ALPHA) / fmaxf((float)val, 1e-12f);
        lcur[tid] = start;
        cursor[node] = start + lcnt[tid];   // overflow edges fill after in-bucket ones
    }
    __syncthreads();

    for (int i = tid; i < n; i += 256) {
        unsigned u = bb[i];
        int p = atomicAdd(&lcur[u >> 17], 1);
        col[p] = (int)(u & 0x1FFFFu);
    }
}

// ---------------------------------------------------------------------------
// overflow fixup (normally a no-op: ocount == 0)
// ---------------------------------------------------------------------------
__global__ void overflow_fix(const int* __restrict__ ocount, const int* __restrict__ obuf,
                             int* __restrict__ cursor, int* __restrict__ col) {
    int oc = *ocount; if (oc > OCAP) oc = OCAP;
    for (int i = threadIdx.x; i < oc; i += 256) {
        int s = obuf[2 * i], d = obuf[2 * i + 1];
        int p = atomicAdd(&cursor[s], 1);
        col[p] = d;
    }
}

// ---------------------------------------------------------------------------
// SpMM: 16 lanes per node, coalesced 64B row gathers, optional fused log_softmax
// ---------------------------------------------------------------------------
template <bool LSM>
__global__ void spmm_kernel(const int* __restrict__ row_ptr,
                            const int* __restrict__ col,
                            const float* __restrict__ scale,
                            const float* __restrict__ Lin,
                            const float* __restrict__ local,
                            float* __restrict__ Lout) {
    int tid = blockIdx.x * 256 + threadIdx.x;
    int g = tid >> 4;
    int lane = tid & 15;
    if (g >= N_NODES) return;
    int wl = threadIdx.x & 63;
    int gbase = wl & 48;

    int s = row_ptr[g], e = row_ptr[g + 1];
    float acc = 0.f;
    for (int base = s; base < e; base += 16) {
        int cv = (base + lane < e) ? col[base + lane] : 0;
        int m = e - base; if (m > 16) m = 16;
        for (int j = 0; j < m; ++j) {
            int c = __shfl(cv, gbase + j);
            acc += Lin[(size_t)c * N_CLASS + lane];
        }
    }
    float r = scale[g] * acc + ALPHA * local[(size_t)g * N_CLASS + lane];
    if (!LSM) {
        Lout[(size_t)g * N_CLASS + lane] = r;
    } else {
        float mx = r;
#pragma unroll
        for (int off = 8; off >= 1; off >>= 1) mx = fmaxf(mx, __shfl_xor(mx, off));
        float ex = expf(r - mx);
        float sm = ex;
#pragma unroll
        for (int off = 8; off >= 1; off >>= 1) sm += __shfl_xor(sm, off);
        Lout[(size_t)g * N_CLASS + lane] = r - mx - logf(sm);
    }
}

// ---------------------------------------------------------------------------
extern "C" void kernel_launch(void* const* d_in, const int* in_sizes, int n_in,
                              void* d_out, int out_size, void* d_ws, size_t ws_size,
                              hipStream_t stream) {
    const float* x    = (const float*)d_in[0];
    const float* W1   = (const float*)d_in[1];
    const float* W2   = (const float*)d_in[2];
    const int*   esrc = (const int*)d_in[3];
    const int*   edst = (const int*)d_in[4];
    float* out = (float*)d_out;
    char*  ws  = (char*)d_ws;

    // workspace layout (bytes)
    float*    local   = (float*)   (ws + 0);           //  6,400,000
    float*    P1      = (float*)   (ws + 6400000);     //  6,400,000 (ping)
    short*    W1t     = (short*)   (ws + 6400000);     //  overlays P1 (dead until spmm1)
    short*    W2t     = (short*)   (ws + 6531072);     //      4,096
    int*      col     = (int*)     (ws + 12800000);    // 12,800,000
    int*      row_ptr = (int*)     (ws + 25600000);    //    400,004
    float*    scale   = (float*)   (ws + 26000004);    //    400,000
    int*      cursor  = (int*)     (ws + 26400004);    //    400,000
    int*      odeg    = (int*)     (ws + 26800004);    //    400,000  -- memset region start
    int*      bcount  = (int*)     (ws + 27200004);    //      3,128
    int*      ocount  = (int*)     (ws + 27203132);    //          4  -- memset region end
    int*      bbase   = (int*)     (ws + 27203136);    //      3,128
    int*      obuf    = (int*)     (ws + 27206264);    //    524,288
    unsigned* bbuf    = (unsigned*)(ws + 27730944);    // 14,413,824 (782*4608*4) -> end ~42.1 MB

    hipMemsetAsync(odeg, 0, 403132, stream);   // odeg + bcount + ocount

    prep_kernel<<<(N_FEAT * HIDDEN + HIDDEN * N_CLASS + 255) / 256, 256, 0, stream>>>(W1, W2, W1t, W2t);
    mlp_mfma<<<(N_NODES + 127) / 128, 256, 0, stream>>>(x, W1t, W2t, local);

    bucket_scatter<<<(N_EDGES + 255) / 256, 256, 0, stream>>>(esrc, edst, bcount, bbuf, odeg, ocount, obuf);
    bscan_kernel<<<1, 1024, 0, stream>>>(bcount, bbase, row_ptr);
    bucket_build<<<NB, 256, 0, stream>>>(bbuf, bcount, bbase, odeg, row_ptr, scale, cursor, col);
    overflow_fix<<<1, 256, 0, stream>>>(ocount, obuf, cursor, col);

    const int sgrid = (N_NODES * 16 + 255) / 256;
    spmm_kernel<false><<<sgrid, 256, 0, stream>>>(row_ptr, col, scale, local, local, P1);
    spmm_kernel<true ><<<sgrid, 256, 0, stream>>>(row_ptr, col, scale, P1, local, out);
}

// Round 4
// 1100.250 us; speedup vs baseline: 1.1032x; 1.1032x over previous
//
#include <hip/hip_runtime.h>
#include <math.h>

#define N_NODES 100000
#define N_FEAT  512
#define HIDDEN  128
#define N_CLASS 16
#define N_EDGES 3200000
#define ALPHA   0.25f

#define NB   782          // ceil(100000/128) buckets of 128 src nodes
#define TILE 8192         // edges per partition/hist block
#define NTB  391          // ceil(N_EDGES / TILE)

typedef __attribute__((ext_vector_type(8))) short short8;
typedef __attribute__((ext_vector_type(4))) float float4v;

__device__ inline short f2b(float f) {
    union { float f; unsigned u; } c; c.f = f;
    unsigned r = c.u + 0x7FFF + ((c.u >> 16) & 1);   // round-to-nearest-even
    return (short)(r >> 16);
}

// ---------------------------------------------------------------------------
// prep: W1t_bf[n=128][k=512] = bf16(W1[k][n]);  W2t_bf[n=16][k=128] = bf16(W2[k][n])
// ---------------------------------------------------------------------------
__global__ void prep_kernel(const float* __restrict__ W1, const float* __restrict__ W2,
                            short* __restrict__ W1t, short* __restrict__ W2t) {
    int t = blockIdx.x * 256 + threadIdx.x;
    if (t < N_FEAT * HIDDEN) {                 // t = n*512 + k
        int k = t & 511, n = t >> 9;
        W1t[t] = f2b(W1[(size_t)k * HIDDEN + n]);
    }
    int t2 = t - N_FEAT * HIDDEN;
    if (t2 >= 0 && t2 < HIDDEN * N_CLASS) {    // t2 = n*128 + k
        int k = t2 & 127, n = t2 >> 7;
        W2t[t2] = f2b(W2[(size_t)k * N_CLASS + n]);
    }
}

// ---------------------------------------------------------------------------
// Fused MLP via MFMA: local = relu(x@W1)@W2, bf16 inputs / fp32 accum
// ---------------------------------------------------------------------------
__global__ __launch_bounds__(256) void mlp_mfma(const float* __restrict__ x,
                                                const short* __restrict__ W1t,
                                                const short* __restrict__ W2t,
                                                float* __restrict__ local_out) {
    __shared__ __align__(16) short As[128 * 32];
    __shared__ __align__(16) short Bts[128 * 32];
    __shared__ __align__(16) short Hs[128 * 136];
    __shared__ __align__(16) short W2ts[16 * 136];

    const int tid  = threadIdx.x;
    const int wave = tid >> 6;
    const int wl   = tid & 63;
    const int lane15 = wl & 15;
    const int quad   = wl >> 4;
    const long block_row = (long)blockIdx.x * 128;

    {
        int n = tid >> 4, koff = (tid & 15) * 8;
        *(short8*)&W2ts[n * 136 + koff] = *(const short8*)&W2t[n * 128 + koff];
    }

    float4v acc[4][4];
#pragma unroll
    for (int i = 0; i < 4; ++i)
#pragma unroll
        for (int j = 0; j < 4; ++j) acc[i][j] = (float4v){0.f, 0.f, 0.f, 0.f};

    const int wr0 = (wave >> 1) * 64;
    const int wc0 = (wave & 1) * 64;

    for (int k0 = 0; k0 < N_FEAT; k0 += 32) {
#pragma unroll
        for (int l = 0; l < 2; ++l) {
            int c = tid + l * 256;
            int row = c >> 2, off = (c & 3) * 8;
            long grow = block_row + row;
            float4 v0 = make_float4(0.f, 0.f, 0.f, 0.f), v1 = v0;
            if (grow < N_NODES) {
                const float* p = x + grow * N_FEAT + k0 + off;
                v0 = *(const float4*)p;
                v1 = *(const float4*)(p + 4);
            }
            short8 h;
            h[0] = f2b(v0.x); h[1] = f2b(v0.y); h[2] = f2b(v0.z); h[3] = f2b(v0.w);
            h[4] = f2b(v1.x); h[5] = f2b(v1.y); h[6] = f2b(v1.z); h[7] = f2b(v1.w);
            *(short8*)&As[row * 32 + off] = h;
        }
#pragma unroll
        for (int l = 0; l < 2; ++l) {
            int c = tid + l * 256;
            int n = c >> 2, koff = (c & 3) * 8;
            *(short8*)&Bts[n * 32 + koff] = *(const short8*)&W1t[n * 512 + k0 + koff];
        }
        __syncthreads();

        short8 af[4], bfr[4];
#pragma unroll
        for (int i = 0; i < 4; ++i)
            af[i] = *(short8*)&As[(wr0 + i * 16 + lane15) * 32 + quad * 8];
#pragma unroll
        for (int j = 0; j < 4; ++j)
            bfr[j] = *(short8*)&Bts[(wc0 + j * 16 + lane15) * 32 + quad * 8];
#pragma unroll
        for (int i = 0; i < 4; ++i)
#pragma unroll
            for (int j = 0; j < 4; ++j)
                acc[i][j] = __builtin_amdgcn_mfma_f32_16x16x32_bf16(af[i], bfr[j], acc[i][j], 0, 0, 0);
        __syncthreads();
    }

#pragma unroll
    for (int i = 0; i < 4; ++i)
#pragma unroll
        for (int j = 0; j < 4; ++j)
#pragma unroll
            for (int r = 0; r < 4; ++r) {
                int row = wr0 + i * 16 + quad * 4 + r;
                int colh = wc0 + j * 16 + lane15;
                Hs[row * 136 + colh] = f2b(fmaxf(acc[i][j][r], 0.f));
            }
    __syncthreads();

    float4v acc2[2];
    acc2[0] = (float4v){0.f, 0.f, 0.f, 0.f};
    acc2[1] = acc2[0];
#pragma unroll
    for (int ks = 0; ks < 4; ++ks) {
        short8 a0 = *(short8*)&Hs[(wave * 32 + lane15) * 136 + ks * 32 + quad * 8];
        short8 a1 = *(short8*)&Hs[(wave * 32 + 16 + lane15) * 136 + ks * 32 + quad * 8];
        short8 b  = *(short8*)&W2ts[lane15 * 136 + ks * 32 + quad * 8];
        acc2[0] = __builtin_amdgcn_mfma_f32_16x16x32_bf16(a0, b, acc2[0], 0, 0, 0);
        acc2[1] = __builtin_amdgcn_mfma_f32_16x16x32_bf16(a1, b, acc2[1], 0, 0, 0);
    }
#pragma unroll
    for (int i2 = 0; i2 < 2; ++i2)
#pragma unroll
        for (int r = 0; r < 4; ++r) {
            long grow = block_row + wave * 32 + i2 * 16 + quad * 4 + r;
            if (grow < N_NODES)
                local_out[grow * N_CLASS + lane15] = acc2[i2][r];
        }
}

// ---------------------------------------------------------------------------
// btot_hist: per-bucket edge totals via LDS histogram + one global atomic per
// (block,bucket). 306K spread atomics vs round-3's 3.2M over 782 addresses.
// ---------------------------------------------------------------------------
__global__ __launch_bounds__(256) void btot_hist(const int* __restrict__ src,
                                                 int* __restrict__ btot) {
    __shared__ int cnt[NB];
    const int tid = threadIdx.x;
    for (int i = tid; i < NB; i += 256) cnt[i] = 0;
    __syncthreads();
    const int e0 = blockIdx.x * TILE;
    int n = N_EDGES - e0; if (n > TILE) n = TILE;
    for (int i = tid; i < n; i += 256)
        atomicAdd(&cnt[src[e0 + i] >> 7], 1);
    __syncthreads();
    for (int i = tid; i < NB; i += 256)
        if (cnt[i]) atomicAdd(&btot[i], cnt[i]);
}

// ---------------------------------------------------------------------------
// bscan: exclusive scan of 782 bucket totals (3 KB — latency-trivial single block)
// ---------------------------------------------------------------------------
__global__ __launch_bounds__(1024) void bscan_kernel(const int* __restrict__ btot,
                                                     int* __restrict__ bbase,
                                                     int* __restrict__ cursor) {
    __shared__ int s[1024];
    int tid = threadIdx.x;
    int v = (tid < NB) ? btot[tid] : 0;
    s[tid] = v;
    __syncthreads();
    for (int off = 1; off < 1024; off <<= 1) {
        int t = (tid >= off) ? s[tid - off] : 0;
        __syncthreads();
        s[tid] += t;
        __syncthreads();
    }
    if (tid < NB) { bbase[tid] = s[tid] - v; cursor[tid] = s[tid] - v; }
}

// ---------------------------------------------------------------------------
// partition: LDS rank + reorder + coalesced flush into exact bucket windows.
// No per-element global atomics; no overflow path (windows are exact-size).
// ---------------------------------------------------------------------------
__global__ __launch_bounds__(256) void partition_kernel(const int* __restrict__ src,
                                                        const int* __restrict__ dst,
                                                        int* __restrict__ cursor,
                                                        unsigned* __restrict__ bbuf) {
    __shared__ unsigned sbuf[TILE];            // 32 KB reordered packed edges
    __shared__ unsigned short sbkt[TILE];      // 16 KB bucket id per slot
    __shared__ int cnt[1024];                  // 4 KB (NB padded)
    __shared__ int off[1024];                  // 4 KB
    __shared__ int gbase[NB];                  // 3.1 KB
    __shared__ int psum[256];                  // 1 KB

    const int tid = threadIdx.x;
    const int e0 = blockIdx.x * TILE;
    int n = N_EDGES - e0; if (n > TILE) n = TILE;

    for (int i = tid; i < 1024; i += 256) cnt[i] = 0;
    __syncthreads();

    unsigned pk[32]; int br[32];
#pragma unroll
    for (int k = 0; k < 32; ++k) {
        int i = tid + k * 256;
        br[k] = -1;
        if (i < n) {
            int s = src[e0 + i], d = dst[e0 + i];
            int b = s >> 7;
            int r = atomicAdd(&cnt[b], 1);       // rank within (block,bucket)
            pk[k] = ((unsigned)(s & 127) << 17) | (unsigned)d;
            br[k] = (b << 13) | r;               // r < 8192 fits 13 bits
        }
    }
    __syncthreads();

    // exclusive scan of cnt[0..1024) -> off  (4 entries/thread + 256-wide scan)
    int b4 = tid * 4;
    int c0 = cnt[b4], c1 = cnt[b4 + 1], c2 = cnt[b4 + 2], c3 = cnt[b4 + 3];
    int tsum = c0 + c1 + c2 + c3;
    psum[tid] = tsum;
    __syncthreads();
    for (int o = 1; o < 256; o <<= 1) {
        int t = (tid >= o) ? psum[tid - o] : 0;
        __syncthreads();
        psum[tid] += t;
        __syncthreads();
    }
    int run = psum[tid] - tsum;
    off[b4] = run; off[b4 + 1] = run + c0;
    off[b4 + 2] = run + c0 + c1; off[b4 + 3] = run + c0 + c1 + c2;
    __syncthreads();

    // reserve exact global windows (one atomic per present bucket)
    for (int b = tid; b < NB; b += 256) {
        int c = cnt[b];
        if (c > 0) gbase[b] = atomicAdd(&cursor[b], c);
    }

    // reorder into LDS
#pragma unroll
    for (int k = 0; k < 32; ++k) {
        if (br[k] >= 0) {
            int b = br[k] >> 13, r = br[k] & 8191;
            int slot = off[b] + r;
            sbuf[slot] = pk[k];
            sbkt[slot] = (unsigned short)b;
        }
    }
    __syncthreads();

    // coalesced flush: consecutive slots of a bucket -> consecutive global addrs
    for (int i = tid; i < n; i += 256) {
        int b = sbkt[i];
        bbuf[gbase[b] + (i - off[b])] = sbuf[i];
    }
}

// ---------------------------------------------------------------------------
// spmm_bucket: one block per 128-node bucket. Edges staged to LDS; 16 lanes
// per edge gather Lin[dst] (coalesced 64B) and ds_add_f32 into acc[128][17].
// Degree counted in LDS -> scale computed inline. LSM pass fuses log_softmax.
// ---------------------------------------------------------------------------
template <bool LSM>
__global__ __launch_bounds__(256) void spmm_bucket(const unsigned* __restrict__ bbuf,
                                                   const int* __restrict__ bbase,
                                                   const int* __restrict__ bend,
                                                   const float* __restrict__ Lin,
                                                   const float* __restrict__ local,
                                                   float* __restrict__ Lout) {
    __shared__ float acc[128 * 17];    // padded: bank = (s*17+c)%32 varies with s
    __shared__ int dcnt[128];
    __shared__ unsigned ebuf[4096];

    const int tid = threadIdx.x;
    const int b = blockIdx.x;
    const int node0 = b << 7;
    const int lane = tid & 15;
    const int g = tid >> 4;            // 16 edge-groups

    for (int i = tid; i < 128 * 17; i += 256) acc[i] = 0.f;
    if (tid < 128) dcnt[tid] = 0;
    __syncthreads();

    const int s = bbase[b], e = bend[b];
    for (int cs = s; cs < e; cs += 4096) {
        int m = e - cs; if (m > 4096) m = 4096;
        for (int j = tid; j < m; j += 256) ebuf[j] = bbuf[cs + j];
        __syncthreads();
        for (int i = g; i < m; i += 16) {
            unsigned u = ebuf[i];
            int sl = u >> 17;
            int d  = u & 0x1FFFF;
            float v = Lin[(size_t)d * N_CLASS + lane];
            atomicAdd(&acc[sl * 17 + lane], v);
            if (lane == 0) atomicAdd(&dcnt[sl], 1);
        }
        __syncthreads();
    }

    // epilogue: 8 group-uniform iterations over the 128 nodes
    for (int nd = g; nd < 128; nd += 16) {
        int node = node0 + nd;
        if (node >= N_NODES) continue;   // group-uniform: shfl below stays safe
        float sc = (1.0f - ALPHA) / fmaxf((float)dcnt[nd], 1e-12f);
        float r = sc * acc[nd * 17 + lane] + ALPHA * local[(size_t)node * N_CLASS + lane];
        if (!LSM) {
            Lout[(size_t)node * N_CLASS + lane] = r;
        } else {
            float mx = r;
#pragma unroll
            for (int o = 8; o >= 1; o >>= 1) mx = fmaxf(mx, __shfl_xor(mx, o));
            float ex = expf(r - mx);
            float sm = ex;
#pragma unroll
            for (int o = 8; o >= 1; o >>= 1) sm += __shfl_xor(sm, o);
            Lout[(size_t)node * N_CLASS + lane] = r - mx - logf(sm);
        }
    }
}

// ---------------------------------------------------------------------------
extern "C" void kernel_launch(void* const* d_in, const int* in_sizes, int n_in,
                              void* d_out, int out_size, void* d_ws, size_t ws_size,
                              hipStream_t stream) {
    const float* x    = (const float*)d_in[0];
    const float* W1   = (const float*)d_in[1];
    const float* W2   = (const float*)d_in[2];
    const int*   esrc = (const int*)d_in[3];
    const int*   edst = (const int*)d_in[4];
    float* out = (float*)d_out;
    char*  ws  = (char*)d_ws;

    // workspace layout (bytes)
    float*    local  = (float*)   (ws + 0);           //  6,400,000
    float*    P1     = (float*)   (ws + 6400000);     //  6,400,000 (ping)
    short*    W1t    = (short*)   (ws + 6400000);     //  overlays P1 (dead until spmm1)
    short*    W2t    = (short*)   (ws + 6531072);     //      4,096
    unsigned* bbuf   = (unsigned*)(ws + 12800000);    // 12,800,000
    int*      btot   = (int*)     (ws + 25600000);    //      3,128  -- memset
    int*      bbase  = (int*)     (ws + 25603128);    //      3,128
    int*      cursor = (int*)     (ws + 25606256);    //      3,128  (end ~25.6 MB)

    hipMemsetAsync(btot, 0, NB * sizeof(int), stream);

    prep_kernel<<<(N_FEAT * HIDDEN + HIDDEN * N_CLASS + 255) / 256, 256, 0, stream>>>(W1, W2, W1t, W2t);
    mlp_mfma<<<(N_NODES + 127) / 128, 256, 0, stream>>>(x, W1t, W2t, local);

    btot_hist<<<NTB, 256, 0, stream>>>(esrc, btot);
    bscan_kernel<<<1, 1024, 0, stream>>>(btot, bbase, cursor);
    partition_kernel<<<NTB, 256, 0, stream>>>(esrc, edst, cursor, bbuf);

    spmm_bucket<false><<<NB, 256, 0, stream>>>(bbuf, bbase, cursor, local, local, P1);
    spmm_bucket<true ><<<NB, 256, 0, stream>>>(bbuf, bbase, cursor, P1, local, out);
}

// Round 5
// 1060.356 us; speedup vs baseline: 1.1447x; 1.0376x over previous
//
#include <hip/hip_runtime.h>
#include <math.h>

#define N_NODES 100000
#define N_FEAT  512
#define HIDDEN  128
#define N_CLASS 16
#define N_EDGES 3200000
#define ALPHA   0.25f

#define NB   782          // ceil(100000/128) buckets of 128 src nodes
#define TILE 8192         // edges per partition/hist block
#define NTB  391          // ceil(N_EDGES / TILE)

typedef __attribute__((ext_vector_type(8))) short short8;
typedef __attribute__((ext_vector_type(4))) float float4v;

__device__ inline short f2b(float f) {
    union { float f; unsigned u; } c; c.f = f;
    unsigned r = c.u + 0x7FFF + ((c.u >> 16) & 1);   // round-to-nearest-even
    return (short)(r >> 16);
}
__device__ inline float b2f(unsigned short h) {
    union { unsigned u; float f; } c; c.u = ((unsigned)h) << 16;
    return c.f;
}

// ---------------------------------------------------------------------------
// prep: W1t_bf[n=128][k=512] = bf16(W1[k][n]);  W2t_bf[n=16][k=128] = bf16(W2[k][n])
// ---------------------------------------------------------------------------
__global__ void prep_kernel(const float* __restrict__ W1, const float* __restrict__ W2,
                            short* __restrict__ W1t, short* __restrict__ W2t) {
    int t = blockIdx.x * 256 + threadIdx.x;
    if (t < N_FEAT * HIDDEN) {                 // t = n*512 + k
        int k = t & 511, n = t >> 9;
        W1t[t] = f2b(W1[(size_t)k * HIDDEN + n]);
    }
    int t2 = t - N_FEAT * HIDDEN;
    if (t2 >= 0 && t2 < HIDDEN * N_CLASS) {    // t2 = n*128 + k
        int k = t2 & 127, n = t2 >> 7;
        W2t[t2] = f2b(W2[(size_t)k * N_CLASS + n]);
    }
}

// ---------------------------------------------------------------------------
// Fused MLP via MFMA: local = relu(x@W1)@W2, bf16 inputs / fp32 accum.
// Writes fp32 `local` plus a bf16 shadow `Lbf` (the spmm gather table).
// ---------------------------------------------------------------------------
__global__ __launch_bounds__(256) void mlp_mfma(const float* __restrict__ x,
                                                const short* __restrict__ W1t,
                                                const short* __restrict__ W2t,
                                                float* __restrict__ local_out,
                                                unsigned short* __restrict__ Lbf) {
    __shared__ __align__(16) short As[128 * 32];
    __shared__ __align__(16) short Bts[128 * 32];
    __shared__ __align__(16) short Hs[128 * 136];
    __shared__ __align__(16) short W2ts[16 * 136];

    const int tid  = threadIdx.x;
    const int wave = tid >> 6;
    const int wl   = tid & 63;
    const int lane15 = wl & 15;
    const int quad   = wl >> 4;
    const long block_row = (long)blockIdx.x * 128;

    {
        int n = tid >> 4, koff = (tid & 15) * 8;
        *(short8*)&W2ts[n * 136 + koff] = *(const short8*)&W2t[n * 128 + koff];
    }

    float4v acc[4][4];
#pragma unroll
    for (int i = 0; i < 4; ++i)
#pragma unroll
        for (int j = 0; j < 4; ++j) acc[i][j] = (float4v){0.f, 0.f, 0.f, 0.f};

    const int wr0 = (wave >> 1) * 64;
    const int wc0 = (wave & 1) * 64;

    for (int k0 = 0; k0 < N_FEAT; k0 += 32) {
#pragma unroll
        for (int l = 0; l < 2; ++l) {
            int c = tid + l * 256;
            int row = c >> 2, off = (c & 3) * 8;
            long grow = block_row + row;
            float4 v0 = make_float4(0.f, 0.f, 0.f, 0.f), v1 = v0;
            if (grow < N_NODES) {
                const float* p = x + grow * N_FEAT + k0 + off;
                v0 = *(const float4*)p;
                v1 = *(const float4*)(p + 4);
            }
            short8 h;
            h[0] = f2b(v0.x); h[1] = f2b(v0.y); h[2] = f2b(v0.z); h[3] = f2b(v0.w);
            h[4] = f2b(v1.x); h[5] = f2b(v1.y); h[6] = f2b(v1.z); h[7] = f2b(v1.w);
            *(short8*)&As[row * 32 + off] = h;
        }
#pragma unroll
        for (int l = 0; l < 2; ++l) {
            int c = tid + l * 256;
            int n = c >> 2, koff = (c & 3) * 8;
            *(short8*)&Bts[n * 32 + koff] = *(const short8*)&W1t[n * 512 + k0 + koff];
        }
        __syncthreads();

        short8 af[4], bfr[4];
#pragma unroll
        for (int i = 0; i < 4; ++i)
            af[i] = *(short8*)&As[(wr0 + i * 16 + lane15) * 32 + quad * 8];
#pragma unroll
        for (int j = 0; j < 4; ++j)
            bfr[j] = *(short8*)&Bts[(wc0 + j * 16 + lane15) * 32 + quad * 8];
#pragma unroll
        for (int i = 0; i < 4; ++i)
#pragma unroll
            for (int j = 0; j < 4; ++j)
                acc[i][j] = __builtin_amdgcn_mfma_f32_16x16x32_bf16(af[i], bfr[j], acc[i][j], 0, 0, 0);
        __syncthreads();
    }

#pragma unroll
    for (int i = 0; i < 4; ++i)
#pragma unroll
        for (int j = 0; j < 4; ++j)
#pragma unroll
            for (int r = 0; r < 4; ++r) {
                int row = wr0 + i * 16 + quad * 4 + r;
                int colh = wc0 + j * 16 + lane15;
                Hs[row * 136 + colh] = f2b(fmaxf(acc[i][j][r], 0.f));
            }
    __syncthreads();

    float4v acc2[2];
    acc2[0] = (float4v){0.f, 0.f, 0.f, 0.f};
    acc2[1] = acc2[0];
#pragma unroll
    for (int ks = 0; ks < 4; ++ks) {
        short8 a0 = *(short8*)&Hs[(wave * 32 + lane15) * 136 + ks * 32 + quad * 8];
        short8 a1 = *(short8*)&Hs[(wave * 32 + 16 + lane15) * 136 + ks * 32 + quad * 8];
        short8 b  = *(short8*)&W2ts[lane15 * 136 + ks * 32 + quad * 8];
        acc2[0] = __builtin_amdgcn_mfma_f32_16x16x32_bf16(a0, b, acc2[0], 0, 0, 0);
        acc2[1] = __builtin_amdgcn_mfma_f32_16x16x32_bf16(a1, b, acc2[1], 0, 0, 0);
    }
#pragma unroll
    for (int i2 = 0; i2 < 2; ++i2)
#pragma unroll
        for (int r = 0; r < 4; ++r) {
            long grow = block_row + wave * 32 + i2 * 16 + quad * 4 + r;
            if (grow < N_NODES) {
                float v = acc2[i2][r];
                local_out[grow * N_CLASS + lane15] = v;
                Lbf[grow * N_CLASS + lane15] = (unsigned short)f2b(v);
            }
        }
}

// ---------------------------------------------------------------------------
// btot_hist: per-bucket edge totals via LDS histogram + one global atomic per
// (block,bucket).
// ---------------------------------------------------------------------------
__global__ __launch_bounds__(256) void btot_hist(const int* __restrict__ src,
                                                 int* __restrict__ btot) {
    __shared__ int cnt[NB];
    const int tid = threadIdx.x;
    for (int i = tid; i < NB; i += 256) cnt[i] = 0;
    __syncthreads();
    const int e0 = blockIdx.x * TILE;
    int n = N_EDGES - e0; if (n > TILE) n = TILE;
    for (int i = tid; i < n; i += 256)
        atomicAdd(&cnt[src[e0 + i] >> 7], 1);
    __syncthreads();
    for (int i = tid; i < NB; i += 256)
        if (cnt[i]) atomicAdd(&btot[i], cnt[i]);
}

// ---------------------------------------------------------------------------
// bscan: exclusive scan of 782 bucket totals (single block, latency-trivial)
// ---------------------------------------------------------------------------
__global__ __launch_bounds__(1024) void bscan_kernel(const int* __restrict__ btot,
                                                     int* __restrict__ bbase,
                                                     int* __restrict__ cursor) {
    __shared__ int s[1024];
    int tid = threadIdx.x;
    int v = (tid < NB) ? btot[tid] : 0;
    s[tid] = v;
    __syncthreads();
    for (int off = 1; off < 1024; off <<= 1) {
        int t = (tid >= off) ? s[tid - off] : 0;
        __syncthreads();
        s[tid] += t;
        __syncthreads();
    }
    if (tid < NB) { bbase[tid] = s[tid] - v; cursor[tid] = s[tid] - v; }
}

// ---------------------------------------------------------------------------
// partition: LDS rank + reorder + coalesced flush into exact bucket windows.
// ---------------------------------------------------------------------------
__global__ __launch_bounds__(256) void partition_kernel(const int* __restrict__ src,
                                                        const int* __restrict__ dst,
                                                        int* __restrict__ cursor,
                                                        unsigned* __restrict__ bbuf) {
    __shared__ unsigned sbuf[TILE];
    __shared__ unsigned short sbkt[TILE];
    __shared__ int cnt[1024];
    __shared__ int off[1024];
    __shared__ int gbase[NB];
    __shared__ int psum[256];

    const int tid = threadIdx.x;
    const int e0 = blockIdx.x * TILE;
    int n = N_EDGES - e0; if (n > TILE) n = TILE;

    for (int i = tid; i < 1024; i += 256) cnt[i] = 0;
    __syncthreads();

    unsigned pk[32]; int br[32];
#pragma unroll
    for (int k = 0; k < 32; ++k) {
        int i = tid + k * 256;
        br[k] = -1;
        if (i < n) {
            int s = src[e0 + i], d = dst[e0 + i];
            int b = s >> 7;
            int r = atomicAdd(&cnt[b], 1);
            pk[k] = ((unsigned)(s & 127) << 17) | (unsigned)d;
            br[k] = (b << 13) | r;
        }
    }
    __syncthreads();

    int b4 = tid * 4;
    int c0 = cnt[b4], c1 = cnt[b4 + 1], c2 = cnt[b4 + 2], c3 = cnt[b4 + 3];
    int tsum = c0 + c1 + c2 + c3;
    psum[tid] = tsum;
    __syncthreads();
    for (int o = 1; o < 256; o <<= 1) {
        int t = (tid >= o) ? psum[tid - o] : 0;
        __syncthreads();
        psum[tid] += t;
        __syncthreads();
    }
    int run = psum[tid] - tsum;
    off[b4] = run; off[b4 + 1] = run + c0;
    off[b4 + 2] = run + c0 + c1; off[b4 + 3] = run + c0 + c1 + c2;
    __syncthreads();

    for (int b = tid; b < NB; b += 256) {
        int c = cnt[b];
        if (c > 0) gbase[b] = atomicAdd(&cursor[b], c);
    }

#pragma unroll
    for (int k = 0; k < 32; ++k) {
        if (br[k] >= 0) {
            int b = br[k] >> 13, r = br[k] & 8191;
            int slot = off[b] + r;
            sbuf[slot] = pk[k];
            sbkt[slot] = (unsigned short)b;
        }
    }
    __syncthreads();

    for (int i = tid; i < n; i += 256) {
        int b = sbkt[i];
        bbuf[gbase[b] + (i - off[b])] = sbuf[i];
    }
}

// ---------------------------------------------------------------------------
// spmm_bucket: one block (512 thr) per 128-node bucket. Lane-PAIR per edge:
// each lane loads one 16 B half-row (bf16x8) from the L2-resident bf16 table,
// converts, and ds_adds 8 floats. Unrolled x2 for 2 gathers in flight.
// PASS 1: count degrees, write scale + bf16 result. PASS 2: read scale,
// fused log_softmax, write fp32 out.
// ---------------------------------------------------------------------------
template <int PASS>
__global__ __launch_bounds__(512) void spmm_bucket(const unsigned* __restrict__ bbuf,
                                                   const int* __restrict__ bbase,
                                                   const int* __restrict__ bend,
                                                   const unsigned short* __restrict__ Ltab,
                                                   const float* __restrict__ local,
                                                   float* __restrict__ scale,
                                                   unsigned short* __restrict__ out_bf,
                                                   float* __restrict__ out_f32) {
    __shared__ float acc[128 * 17];     // 8704 B
    __shared__ int dcnt[128];           //  512 B
    __shared__ unsigned ebuf[4096];     // 16 KB

    const int tid = threadIdx.x;
    const int b = blockIdx.x;
    const int node0 = b << 7;

    for (int i = tid; i < 128 * 17; i += 512) acc[i] = 0.f;
    if (tid < 128) dcnt[tid] = 0;
    __syncthreads();

    const int s = bbase[b], e = bend[b];
    const int slot = tid >> 1;      // 256 edge slots
    const int half = tid & 1;       // which 16 B half-row

    for (int cs = s; cs < e; cs += 4096) {
        int m = e - cs; if (m > 4096) m = 4096;
        for (int j = tid; j < m; j += 512) ebuf[j] = bbuf[cs + j];
        __syncthreads();
        for (int i = slot; i < m; i += 512) {
            unsigned u0 = ebuf[i];
            int i1 = i + 256;
            bool has1 = (i1 < m);
            unsigned u1 = has1 ? ebuf[i1] : u0;
            int sl0 = u0 >> 17, d0 = u0 & 0x1FFFF;
            int sl1 = u1 >> 17, d1 = u1 & 0x1FFFF;
            short8 r0 = *(const short8*)&Ltab[(size_t)d0 * N_CLASS + half * 8];
            short8 r1 = *(const short8*)&Ltab[(size_t)d1 * N_CLASS + half * 8];
            float* a0 = &acc[sl0 * 17 + half * 8];
#pragma unroll
            for (int c = 0; c < 8; ++c)
                atomicAdd(&a0[c], b2f((unsigned short)r0[c]));
            if (PASS == 1 && half == 0) atomicAdd(&dcnt[sl0], 1);
            if (has1) {
                float* a1 = &acc[sl1 * 17 + half * 8];
#pragma unroll
                for (int c = 0; c < 8; ++c)
                    atomicAdd(&a1[c], b2f((unsigned short)r1[c]));
                if (PASS == 1 && half == 0) atomicAdd(&dcnt[sl1], 1);
            }
        }
        __syncthreads();
    }

    // epilogue: 16 lanes per node
    const int g = tid >> 4, lane = tid & 15;
    for (int nd = g; nd < 128; nd += 32) {
        int node = node0 + nd;
        if (node >= N_NODES) continue;   // group-uniform
        float sc;
        if (PASS == 1) sc = (1.0f - ALPHA) / fmaxf((float)dcnt[nd], 1e-12f);
        else           sc = scale[node];
        float r = sc * acc[nd * 17 + lane] + ALPHA * local[(size_t)node * N_CLASS + lane];
        if (PASS == 1) {
            if (lane == 0) scale[node] = sc;
            out_bf[(size_t)node * N_CLASS + lane] = (unsigned short)f2b(r);
        } else {
            float mx = r;
#pragma unroll
            for (int o = 8; o >= 1; o >>= 1) mx = fmaxf(mx, __shfl_xor(mx, o));
            float ex = expf(r - mx);
            float sm = ex;
#pragma unroll
            for (int o = 8; o >= 1; o >>= 1) sm += __shfl_xor(sm, o);
            out_f32[(size_t)node * N_CLASS + lane] = r - mx - logf(sm);
        }
    }
}

// ---------------------------------------------------------------------------
extern "C" void kernel_launch(void* const* d_in, const int* in_sizes, int n_in,
                              void* d_out, int out_size, void* d_ws, size_t ws_size,
                              hipStream_t stream) {
    const float* x    = (const float*)d_in[0];
    const float* W1   = (const float*)d_in[1];
    const float* W2   = (const float*)d_in[2];
    const int*   esrc = (const int*)d_in[3];
    const int*   edst = (const int*)d_in[4];
    float* out = (float*)d_out;
    char*  ws  = (char*)d_ws;

    // workspace layout (bytes)
    float*          local  = (float*)         (ws + 0);          //  6,400,000
    unsigned short* Lbf    = (unsigned short*)(ws + 6400000);    //  3,200,000
    unsigned short* P1bf   = (unsigned short*)(ws + 9600000);    //  3,200,000
    float*          scale  = (float*)         (ws + 12800000);   //    400,000
    short*          W1t    = (short*)         (ws + 13200000);   //    131,072
    short*          W2t    = (short*)         (ws + 13331072);   //      4,096
    int*            btot   = (int*)           (ws + 13335168);   //      3,128  -- memset
    int*            bbase  = (int*)           (ws + 13338296);   //      3,128
    int*            cursor = (int*)           (ws + 13341424);   //      3,128
    unsigned*       bbuf   = (unsigned*)      (ws + 13344560);   // 12,800,000 (end ~26.1 MB)

    hipMemsetAsync(btot, 0, NB * sizeof(int), stream);

    prep_kernel<<<(N_FEAT * HIDDEN + HIDDEN * N_CLASS + 255) / 256, 256, 0, stream>>>(W1, W2, W1t, W2t);
    mlp_mfma<<<(N_NODES + 127) / 128, 256, 0, stream>>>(x, W1t, W2t, local, Lbf);

    btot_hist<<<NTB, 256, 0, stream>>>(esrc, btot);
    bscan_kernel<<<1, 1024, 0, stream>>>(btot, bbase, cursor);
    partition_kernel<<<NTB, 256, 0, stream>>>(esrc, edst, cursor, bbuf);

    spmm_bucket<1><<<NB, 512, 0, stream>>>(bbuf, bbase, cursor, Lbf,  local, scale, P1bf, nullptr);
    spmm_bucket<2><<<NB, 512, 0, stream>>>(bbuf, bbase, cursor, P1bf, local, scale, nullptr, out);
}

// Round 6
// 431.799 us; speedup vs baseline: 2.8110x; 2.4557x over previous
//
#include <hip/hip_runtime.h>
#include <math.h>

#define N_NODES 100000
#define N_FEAT  512
#define HIDDEN  128
#define N_CLASS 16
#define N_EDGES 3200000
#define ALPHA   0.25f

#define NB   782          // ceil(100000/128) buckets of 128 src nodes
#define CAP  5120         // fixed bucket window (mean 4096, sigma 64 -> +16 sigma)
#define TILE 8192         // edges per partition block
#define NTB  391          // ceil(N_EDGES / TILE)

typedef __attribute__((ext_vector_type(8))) short short8;
typedef __attribute__((ext_vector_type(4))) float float4v;

__device__ inline short f2b(float f) {
    union { float f; unsigned u; } c; c.f = f;
    unsigned r = c.u + 0x7FFF + ((c.u >> 16) & 1);   // round-to-nearest-even
    return (short)(r >> 16);
}

// ---------------------------------------------------------------------------
// prep: bf16-transpose W1/W2 + init bucket cursors (no memset needed)
// ---------------------------------------------------------------------------
__global__ void prep_kernel(const float* __restrict__ W1, const float* __restrict__ W2,
                            short* __restrict__ W1t, short* __restrict__ W2t,
                            int* __restrict__ cursor) {
    int t = blockIdx.x * 256 + threadIdx.x;
    if (t < N_FEAT * HIDDEN) {                 // t = n*512 + k
        int k = t & 511, n = t >> 9;
        W1t[t] = f2b(W1[(size_t)k * HIDDEN + n]);
    }
    int t2 = t - N_FEAT * HIDDEN;
    if (t2 >= 0 && t2 < HIDDEN * N_CLASS) {    // t2 = n*128 + k
        int k = t2 & 127, n = t2 >> 7;
        W2t[t2] = f2b(W2[(size_t)k * N_CLASS + n]);
    }
    if (t < NB) cursor[t] = t * CAP;
}

// ---------------------------------------------------------------------------
// Fused MLP via MFMA: local = relu(x@W1)@W2, bf16 inputs / fp32 accum.
// Writes fp32 `local` plus a bf16 shadow `Lbf` (the spmm gather table).
// ---------------------------------------------------------------------------
__global__ __launch_bounds__(256) void mlp_mfma(const float* __restrict__ x,
                                                const short* __restrict__ W1t,
                                                const short* __restrict__ W2t,
                                                float* __restrict__ local_out,
                                                unsigned short* __restrict__ Lbf) {
    __shared__ __align__(16) short As[128 * 32];
    __shared__ __align__(16) short Bts[128 * 32];
    __shared__ __align__(16) short Hs[128 * 136];
    __shared__ __align__(16) short W2ts[16 * 136];

    const int tid  = threadIdx.x;
    const int wave = tid >> 6;
    const int wl   = tid & 63;
    const int lane15 = wl & 15;
    const int quad   = wl >> 4;
    const long block_row = (long)blockIdx.x * 128;

    {
        int n = tid >> 4, koff = (tid & 15) * 8;
        *(short8*)&W2ts[n * 136 + koff] = *(const short8*)&W2t[n * 128 + koff];
    }

    float4v acc[4][4];
#pragma unroll
    for (int i = 0; i < 4; ++i)
#pragma unroll
        for (int j = 0; j < 4; ++j) acc[i][j] = (float4v){0.f, 0.f, 0.f, 0.f};

    const int wr0 = (wave >> 1) * 64;
    const int wc0 = (wave & 1) * 64;

    for (int k0 = 0; k0 < N_FEAT; k0 += 32) {
#pragma unroll
        for (int l = 0; l < 2; ++l) {
            int c = tid + l * 256;
            int row = c >> 2, off = (c & 3) * 8;
            long grow = block_row + row;
            float4 v0 = make_float4(0.f, 0.f, 0.f, 0.f), v1 = v0;
            if (grow < N_NODES) {
                const float* p = x + grow * N_FEAT + k0 + off;
                v0 = *(const float4*)p;
                v1 = *(const float4*)(p + 4);
            }
            short8 h;
            h[0] = f2b(v0.x); h[1] = f2b(v0.y); h[2] = f2b(v0.z); h[3] = f2b(v0.w);
            h[4] = f2b(v1.x); h[5] = f2b(v1.y); h[6] = f2b(v1.z); h[7] = f2b(v1.w);
            *(short8*)&As[row * 32 + off] = h;
        }
#pragma unroll
        for (int l = 0; l < 2; ++l) {
            int c = tid + l * 256;
            int n = c >> 2, koff = (c & 3) * 8;
            *(short8*)&Bts[n * 32 + koff] = *(const short8*)&W1t[n * 512 + k0 + koff];
        }
        __syncthreads();

        short8 af[4], bfr[4];
#pragma unroll
        for (int i = 0; i < 4; ++i)
            af[i] = *(short8*)&As[(wr0 + i * 16 + lane15) * 32 + quad * 8];
#pragma unroll
        for (int j = 0; j < 4; ++j)
            bfr[j] = *(short8*)&Bts[(wc0 + j * 16 + lane15) * 32 + quad * 8];
#pragma unroll
        for (int i = 0; i < 4; ++i)
#pragma unroll
            for (int j = 0; j < 4; ++j)
                acc[i][j] = __builtin_amdgcn_mfma_f32_16x16x32_bf16(af[i], bfr[j], acc[i][j], 0, 0, 0);
        __syncthreads();
    }

#pragma unroll
    for (int i = 0; i < 4; ++i)
#pragma unroll
        for (int j = 0; j < 4; ++j)
#pragma unroll
            for (int r = 0; r < 4; ++r) {
                int row = wr0 + i * 16 + quad * 4 + r;
                int colh = wc0 + j * 16 + lane15;
                Hs[row * 136 + colh] = f2b(fmaxf(acc[i][j][r], 0.f));
            }
    __syncthreads();

    float4v acc2[2];
    acc2[0] = (float4v){0.f, 0.f, 0.f, 0.f};
    acc2[1] = acc2[0];
#pragma unroll
    for (int ks = 0; ks < 4; ++ks) {
        short8 a0 = *(short8*)&Hs[(wave * 32 + lane15) * 136 + ks * 32 + quad * 8];
        short8 a1 = *(short8*)&Hs[(wave * 32 + 16 + lane15) * 136 + ks * 32 + quad * 8];
        short8 b  = *(short8*)&W2ts[lane15 * 136 + ks * 32 + quad * 8];
        acc2[0] = __builtin_amdgcn_mfma_f32_16x16x32_bf16(a0, b, acc2[0], 0, 0, 0);
        acc2[1] = __builtin_amdgcn_mfma_f32_16x16x32_bf16(a1, b, acc2[1], 0, 0, 0);
    }
#pragma unroll
    for (int i2 = 0; i2 < 2; ++i2)
#pragma unroll
        for (int r = 0; r < 4; ++r) {
            long grow = block_row + wave * 32 + i2 * 16 + quad * 4 + r;
            if (grow < N_NODES) {
                float v = acc2[i2][r];
                local_out[grow * N_CLASS + lane15] = v;
                Lbf[grow * N_CLASS + lane15] = (unsigned short)f2b(v);
            }
        }
}

// ---------------------------------------------------------------------------
// partition: LDS rank + reorder + coalesced flush into fixed b*CAP windows.
// ---------------------------------------------------------------------------
__global__ __launch_bounds__(256) void partition_kernel(const int* __restrict__ src,
                                                        const int* __restrict__ dst,
                                                        int* __restrict__ cursor,
                                                        unsigned* __restrict__ bbuf) {
    __shared__ unsigned sbuf[TILE];
    __shared__ unsigned short sbkt[TILE];
    __shared__ int cnt[1024];
    __shared__ int off[1024];
    __shared__ int gbase[NB];
    __shared__ int psum[256];

    const int tid = threadIdx.x;
    const int e0 = blockIdx.x * TILE;
    int n = N_EDGES - e0; if (n > TILE) n = TILE;

    for (int i = tid; i < 1024; i += 256) cnt[i] = 0;
    __syncthreads();

    unsigned pk[32]; int br[32];
#pragma unroll
    for (int k = 0; k < 32; ++k) {
        int i = tid + k * 256;
        br[k] = -1;
        if (i < n) {
            int s = src[e0 + i], d = dst[e0 + i];
            int b = s >> 7;
            int r = atomicAdd(&cnt[b], 1);
            pk[k] = ((unsigned)(s & 127) << 17) | (unsigned)d;
            br[k] = (b << 13) | r;
        }
    }
    __syncthreads();

    int b4 = tid * 4;
    int c0 = cnt[b4], c1 = cnt[b4 + 1], c2 = cnt[b4 + 2], c3 = cnt[b4 + 3];
    int tsum = c0 + c1 + c2 + c3;
    psum[tid] = tsum;
    __syncthreads();
    for (int o = 1; o < 256; o <<= 1) {
        int t = (tid >= o) ? psum[tid - o] : 0;
        __syncthreads();
        psum[tid] += t;
        __syncthreads();
    }
    int run = psum[tid] - tsum;
    off[b4] = run; off[b4 + 1] = run + c0;
    off[b4 + 2] = run + c0 + c1; off[b4 + 3] = run + c0 + c1 + c2;
    __syncthreads();

    for (int b = tid; b < NB; b += 256) {
        int c = cnt[b];
        if (c > 0) gbase[b] = atomicAdd(&cursor[b], c);
    }

#pragma unroll
    for (int k = 0; k < 32; ++k) {
        if (br[k] >= 0) {
            int b = br[k] >> 13, r = br[k] & 8191;
            int slot = off[b] + r;
            sbuf[slot] = pk[k];
            sbkt[slot] = (unsigned short)b;
        }
    }
    __syncthreads();

    for (int i = tid; i < n; i += 256) {
        int b = sbkt[i];
        bbuf[gbase[b] + (i - off[b])] = sbuf[i];
    }
}

// ---------------------------------------------------------------------------
// bucket_sort: one block per bucket. Sort bucket's edges by src slot in LDS
// (hist + scan + rank), write back node-contiguous dst list (in place) and
// exact row_start / row_end / scale. All small int LDS atomics (6.4M total).
// ---------------------------------------------------------------------------
__global__ __launch_bounds__(512) void bucket_sort(unsigned* __restrict__ bbuf,
                                                   const int* __restrict__ cursor,
                                                   int* __restrict__ row_start,
                                                   int* __restrict__ row_end,
                                                   float* __restrict__ scale) {
    __shared__ unsigned ein[CAP];      // 20 KB
    __shared__ unsigned eout[CAP];     // 20 KB
    __shared__ int cnt[128], ssc[128], cur[128];

    const int b = blockIdx.x;
    const int tid = threadIdx.x;
    const int base = b * CAP;
    int n = cursor[b] - base; if (n > CAP) n = CAP;

    for (int i = tid; i < n; i += 512) ein[i] = bbuf[base + i];
    if (tid < 128) cnt[tid] = 0;
    __syncthreads();

    for (int i = tid; i < n; i += 512) atomicAdd(&cnt[ein[i] >> 17], 1);
    __syncthreads();

    int v = (tid < 128) ? cnt[tid] : 0;
    if (tid < 128) ssc[tid] = v;
    __syncthreads();
    for (int o = 1; o < 128; o <<= 1) {
        int t = (tid >= o && tid < 128) ? ssc[tid - o] : 0;
        __syncthreads();
        if (tid < 128) ssc[tid] += t;
        __syncthreads();
    }
    if (tid < 128) cur[tid] = ssc[tid] - v;   // exclusive prefix
    __syncthreads();

    for (int i = tid; i < n; i += 512) {
        unsigned u = ein[i];
        int r = atomicAdd(&cur[u >> 17], 1);
        eout[r] = u & 0x1FFFFu;
    }
    __syncthreads();

    for (int i = tid; i < n; i += 512) bbuf[base + i] = eout[i];

    if (tid < 128) {
        int node = (b << 7) + tid;
        if (node < N_NODES) {
            int st = base + ssc[tid] - v;
            row_start[node] = st;
            row_end[node]   = st + v;
            scale[node] = (1.0f - ALPHA) / fmaxf((float)v, 1e-12f);
        }
    }
}

// ---------------------------------------------------------------------------
// spmm_csr: 2 lanes per node; lane gathers 16B (8 bf16 classes) per edge with
// 16 edges in flight (predicated unroll); register accumulation, NO LDS atomics.
// PASS 1 -> bf16 out; PASS 2 -> fused log_softmax, fp32 out.
// ---------------------------------------------------------------------------
template <int PASS>
__global__ __launch_bounds__(512) void spmm_csr(const unsigned* __restrict__ col,
                                                const int* __restrict__ row_start,
                                                const int* __restrict__ row_end,
                                                const float* __restrict__ scale,
                                                const unsigned short* __restrict__ Ltab,
                                                const float* __restrict__ local,
                                                unsigned short* __restrict__ out_bf,
                                                float* __restrict__ out_f32) {
    int t = blockIdx.x * 512 + threadIdx.x;
    int node = t >> 1;
    int half = t & 1;
    if (node >= N_NODES) return;
    const int rs = row_start[node], re = row_end[node];

    float acc[8];
#pragma unroll
    for (int k = 0; k < 8; ++k) acc[k] = 0.f;

    for (int base = rs; base < re; base += 16) {
        int cc[16];
#pragma unroll
        for (int j = 0; j < 16; ++j)
            cc[j] = (base + j < re) ? (int)col[base + j] : -1;
        uint4 g[16];
#pragma unroll
        for (int j = 0; j < 16; ++j) {
            int c = (cc[j] < 0) ? 0 : cc[j];
            g[j] = *(const uint4*)&Ltab[(size_t)c * N_CLASS + half * 8];
        }
#pragma unroll
        for (int j = 0; j < 16; ++j) {
            if (cc[j] >= 0) {
                union { unsigned u; float f; } w;
                w.u = g[j].x << 16;          acc[0] += w.f;
                w.u = g[j].x & 0xFFFF0000u;  acc[1] += w.f;
                w.u = g[j].y << 16;          acc[2] += w.f;
                w.u = g[j].y & 0xFFFF0000u;  acc[3] += w.f;
                w.u = g[j].z << 16;          acc[4] += w.f;
                w.u = g[j].z & 0xFFFF0000u;  acc[5] += w.f;
                w.u = g[j].w << 16;          acc[6] += w.f;
                w.u = g[j].w & 0xFFFF0000u;  acc[7] += w.f;
            }
        }
    }

    const float sc = scale[node];
    const float* lp = &local[(size_t)node * N_CLASS + half * 8];
    float4 l0 = *(const float4*)lp;
    float4 l1 = *(const float4*)(lp + 4);
    float r[8];
    r[0] = sc * acc[0] + ALPHA * l0.x; r[1] = sc * acc[1] + ALPHA * l0.y;
    r[2] = sc * acc[2] + ALPHA * l0.z; r[3] = sc * acc[3] + ALPHA * l0.w;
    r[4] = sc * acc[4] + ALPHA * l1.x; r[5] = sc * acc[5] + ALPHA * l1.y;
    r[6] = sc * acc[6] + ALPHA * l1.z; r[7] = sc * acc[7] + ALPHA * l1.w;

    if (PASS == 1) {
        uint4 o;
        o.x = ((unsigned)(unsigned short)f2b(r[1]) << 16) | (unsigned)(unsigned short)f2b(r[0]);
        o.y = ((unsigned)(unsigned short)f2b(r[3]) << 16) | (unsigned)(unsigned short)f2b(r[2]);
        o.z = ((unsigned)(unsigned short)f2b(r[5]) << 16) | (unsigned)(unsigned short)f2b(r[4]);
        o.w = ((unsigned)(unsigned short)f2b(r[7]) << 16) | (unsigned)(unsigned short)f2b(r[6]);
        *(uint4*)&out_bf[(size_t)node * N_CLASS + half * 8] = o;
    } else {
        float mx = r[0];
#pragma unroll
        for (int k = 1; k < 8; ++k) mx = fmaxf(mx, r[k]);
        mx = fmaxf(mx, __shfl_xor(mx, 1));
        float sm = 0.f;
#pragma unroll
        for (int k = 0; k < 8; ++k) sm += expf(r[k] - mx);
        sm += __shfl_xor(sm, 1);
        float ls = logf(sm) + mx;
        float4 o0 = make_float4(r[0] - ls, r[1] - ls, r[2] - ls, r[3] - ls);
        float4 o1 = make_float4(r[4] - ls, r[5] - ls, r[6] - ls, r[7] - ls);
        float* op = &out_f32[(size_t)node * N_CLASS + half * 8];
        *(float4*)op = o0;
        *(float4*)(op + 4) = o1;
    }
}

// ---------------------------------------------------------------------------
extern "C" void kernel_launch(void* const* d_in, const int* in_sizes, int n_in,
                              void* d_out, int out_size, void* d_ws, size_t ws_size,
                              hipStream_t stream) {
    const float* x    = (const float*)d_in[0];
    const float* W1   = (const float*)d_in[1];
    const float* W2   = (const float*)d_in[2];
    const int*   esrc = (const int*)d_in[3];
    const int*   edst = (const int*)d_in[4];
    float* out = (float*)d_out;
    char*  ws  = (char*)d_ws;

    // workspace layout (bytes)
    float*          local   = (float*)         (ws + 0);          //  6,400,000
    unsigned short* Lbf     = (unsigned short*)(ws + 6400000);    //  3,200,000
    unsigned short* P1bf    = (unsigned short*)(ws + 9600000);    //  3,200,000
    float*          scale   = (float*)         (ws + 12800000);   //    400,000
    int*            rstart  = (int*)           (ws + 13200000);   //    400,000
    int*            rend    = (int*)           (ws + 13600000);   //    400,000
    short*          W1t     = (short*)         (ws + 14000000);   //    131,072
    short*          W2t     = (short*)         (ws + 14131072);   //      4,096
    int*            cursor  = (int*)           (ws + 14135168);   //      3,128
    unsigned*       bbuf    = (unsigned*)      (ws + 14138296);   // 16,015,360 (end ~30.2 MB)

    prep_kernel<<<(N_FEAT * HIDDEN + HIDDEN * N_CLASS + 255) / 256, 256, 0, stream>>>(W1, W2, W1t, W2t, cursor);
    mlp_mfma<<<(N_NODES + 127) / 128, 256, 0, stream>>>(x, W1t, W2t, local, Lbf);

    partition_kernel<<<NTB, 256, 0, stream>>>(esrc, edst, cursor, bbuf);
    bucket_sort<<<NB, 512, 0, stream>>>(bbuf, cursor, rstart, rend, scale);

    const int sgrid = (N_NODES * 2 + 511) / 512;
    spmm_csr<1><<<sgrid, 512, 0, stream>>>(bbuf, rstart, rend, scale, Lbf,  local, P1bf, nullptr);
    spmm_csr<2><<<sgrid, 512, 0, stream>>>(bbuf, rstart, rend, scale, P1bf, local, nullptr, out);
}